// Round 10
// baseline (142.300 us; speedup 1.0000x reference)
//
#include <hip/hip_runtime.h>
#include <cstdint>
#include <cstddef>

#define D_MODEL 512
#define SEQ_T 2048
#define NHEADS 8
#define HDIM 64

typedef __attribute__((ext_vector_type(8))) short bf16x8;
typedef __attribute__((ext_vector_type(4))) short bf16x4;
typedef __attribute__((ext_vector_type(4))) float f32x4;

__device__ __forceinline__ unsigned short f2bf(float f) {
  unsigned int u = __float_as_uint(f);
  u += 0x7FFFu + ((u >> 16) & 1u);
  return (unsigned short)(u >> 16);
}

// pack two f32 -> two bf16 in one uint (round via +0x8000, v_perm)
__device__ __forceinline__ unsigned int pack_bf16(float lo, float hi) {
  unsigned int a = __float_as_uint(lo) + 0x8000u;
  unsigned int b = __float_as_uint(hi) + 0x8000u;
  return __builtin_amdgcn_perm(b, a, 0x07060302u);
}

// Q pre-scaled by 1/sqrt(64) * log2(e) so softmax runs in exp2 domain.
#define QSCALE 0.18033688011112043f
// fixed softmax shift: p = exp2(s - SSHIFT); common factor cancels in O/l.
#define SSHIFT 16.0f

// async global->LDS, 16B per lane. LDS dest = wave-uniform base + lane*16.
__device__ __forceinline__ void async_lds16(const unsigned short* g,
                                            unsigned short* l) {
  __builtin_amdgcn_global_load_lds(
      (const __attribute__((address_space(1))) void*)g,
      (__attribute__((address_space(3))) void*)l, 16, 0, 0);
}

// ---------------------------------------------------------------------------
// Fused prep (r7): [0,2048) cast x -> bf16; [2048,2240) transpose W_qkv;
// [2240,2304) transpose W_out.
// ---------------------------------------------------------------------------
__global__ __launch_bounds__(256) void prep_kernel(
    const float* __restrict__ x, const float* __restrict__ W_qkv,
    const float* __restrict__ W_out, unsigned short* __restrict__ xb,
    unsigned short* __restrict__ Wqkt, unsigned short* __restrict__ Wot) {
  __shared__ float tile[64][65];
  const int bid = blockIdx.x;
  if (bid < 2048) {
    int i = (bid * 256 + threadIdx.x) * 8;
    float4 a = *(const float4*)(x + i);
    float4 b = *(const float4*)(x + i + 4);
    ushort4 lo = {f2bf(a.x), f2bf(a.y), f2bf(a.z), f2bf(a.w)};
    ushort4 hi = {f2bf(b.x), f2bf(b.y), f2bf(b.z), f2bf(b.w)};
    *(ushort4*)(xb + i) = lo;
    *(ushort4*)(xb + i + 4) = hi;
    return;
  }
  const float* src;
  unsigned short* dst;
  int R = 512, C, c0, r0;
  if (bid < 2048 + 192) {
    int t = bid - 2048;
    C = 1536; c0 = (t % 24) * 64; r0 = (t / 24) * 64;
    src = W_qkv; dst = Wqkt;
  } else {
    int t = bid - 2240;
    C = 512; c0 = (t & 7) * 64; r0 = (t >> 3) * 64;
    src = W_out; dst = Wot;
  }
  for (int i = threadIdx.x; i < 64 * 64; i += 256) {
    int r = i >> 6, c = i & 63;
    tile[r][c] = src[(size_t)(r0 + r) * C + c0 + c];
  }
  __syncthreads();
  for (int i = threadIdx.x; i < 64 * 64; i += 256) {
    int c = i >> 6, r = i & 63;
    dst[(size_t)(c0 + c) * R + r0 + r] = f2bf(tile[r][c]);
  }
}

// ---------------------------------------------------------------------------
// Kernel 1 (r7): QKV projection, bf16 MFMA. 128x128 tile, BK=64,
// XOR-swizzled LDS, async staging. Q -> [bh][d][t] packed (pre-scaled);
// V -> [bh][dv][t] packed; K -> [bh][t][d] scalar.
// ---------------------------------------------------------------------------
__global__ __launch_bounds__(256) void gemm_qkv_mfma(
    const unsigned short* __restrict__ xb, const unsigned short* __restrict__ Wt,
    const float* __restrict__ bias, unsigned short* __restrict__ Qtb,
    unsigned short* __restrict__ Kb, unsigned short* __restrict__ Vtb) {
  __shared__ unsigned short As[128 * 64];
  __shared__ unsigned short Bs[128 * 64];
  const int tid = threadIdx.x;
  const int w = tid >> 6, lane = tid & 63;
  const int quad = lane >> 4, l15 = lane & 15;
  const int wm = w >> 1, wn = w & 1;
  const int m0 = blockIdx.x * 128, n0 = blockIdx.y * 128;

  const int srow = tid >> 3;
  const int schunk = (tid & 7) ^ (srow & 7);
  const unsigned short* ga = xb + (size_t)(m0 + srow) * 512 + schunk * 8;
  const unsigned short* gb = Wt + (size_t)(n0 + srow) * 512 + schunk * 8;
  unsigned short* lA = As + tid * 8;
  unsigned short* lB = Bs + tid * 8;

  f32x4 acc[4][4] = {};
  for (int k0 = 0; k0 < 512; k0 += 64) {
#pragma unroll
    for (int rr = 0; rr < 4; ++rr) {
      async_lds16(ga + (size_t)rr * 32 * 512 + k0, lA + rr * 2048);
      async_lds16(gb + (size_t)rr * 32 * 512 + k0, lB + rr * 2048);
    }
    __syncthreads();
    bf16x8 af[4][2], bfr[4][2];
#pragma unroll
    for (int mb = 0; mb < 4; ++mb) {
      int row = wm * 64 + mb * 16 + l15;
#pragma unroll
      for (int kk = 0; kk < 2; ++kk) {
        int slot = (kk * 4 + quad) ^ (row & 7);
        af[mb][kk] = *(const bf16x8*)&As[row * 64 + slot * 8];
      }
    }
#pragma unroll
    for (int nb = 0; nb < 4; ++nb) {
      int row = wn * 64 + nb * 16 + l15;
#pragma unroll
      for (int kk = 0; kk < 2; ++kk) {
        int slot = (kk * 4 + quad) ^ (row & 7);
        bfr[nb][kk] = *(const bf16x8*)&Bs[row * 64 + slot * 8];
      }
    }
#pragma unroll
    for (int mb = 0; mb < 4; ++mb)
#pragma unroll
      for (int nb = 0; nb < 4; ++nb) {
        acc[mb][nb] = __builtin_amdgcn_mfma_f32_16x16x32_bf16(
            af[mb][0], bfr[nb][0], acc[mb][nb], 0, 0, 0);
        acc[mb][nb] = __builtin_amdgcn_mfma_f32_16x16x32_bf16(
            af[mb][1], bfr[nb][1], acc[mb][nb], 0, 0, 0);
      }
    __syncthreads();
  }

  const int cbase = n0 + wn * 64;
  const int three = cbase >> 9;
  const int h = (cbase >> 6) & 7;
  const int bh = ((m0 >> 11) << 3) + h;
  const int t0 = (m0 & 2047) + wm * 64;
  float bv[4];
#pragma unroll
  for (int nb = 0; nb < 4; ++nb) bv[nb] = bias[cbase + nb * 16 + l15];

  if (three == 0) {
#pragma unroll
    for (int mb = 0; mb < 4; ++mb)
#pragma unroll
      for (int nb = 0; nb < 4; ++nb) {
        int trow = t0 + mb * 16 + quad * 4;
        ushort4 v = {f2bf((acc[mb][nb][0] + bv[nb]) * QSCALE),
                     f2bf((acc[mb][nb][1] + bv[nb]) * QSCALE),
                     f2bf((acc[mb][nb][2] + bv[nb]) * QSCALE),
                     f2bf((acc[mb][nb][3] + bv[nb]) * QSCALE)};
        *(ushort4*)(Qtb + ((size_t)bh * HDIM + nb * 16 + l15) * SEQ_T + trow) = v;
      }
  } else if (three == 2) {
#pragma unroll
    for (int mb = 0; mb < 4; ++mb)
#pragma unroll
      for (int nb = 0; nb < 4; ++nb) {
        int trow = t0 + mb * 16 + quad * 4;
        ushort4 v = {f2bf(acc[mb][nb][0] + bv[nb]), f2bf(acc[mb][nb][1] + bv[nb]),
                     f2bf(acc[mb][nb][2] + bv[nb]), f2bf(acc[mb][nb][3] + bv[nb])};
        *(ushort4*)(Vtb + ((size_t)bh * HDIM + nb * 16 + l15) * SEQ_T + trow) = v;
      }
  } else {
#pragma unroll
    for (int mb = 0; mb < 4; ++mb)
#pragma unroll
      for (int nb = 0; nb < 4; ++nb)
#pragma unroll
        for (int r = 0; r < 4; ++r) {
          int trow = t0 + mb * 16 + quad * 4 + r;
          Kb[((size_t)bh * SEQ_T + trow) * HDIM + nb * 16 + l15] =
              f2bf(acc[mb][nb][r] + bv[nb]);
        }
  }
}

// ---------------------------------------------------------------------------
// Kernel 2 (v7): causal flash attention, KEY-SPLIT across waves.
// Wave w owns keys [w*16, w*16+16) of each 64-key tile, ALL 64 q-rows.
// K A-frag: 2 b128/tile; V A-frags: 4 b64/tile; Q B-frags in registers
// (loaded once); P stays IN REGISTERS: S C-layout (row=quad*4+r) is the
// B-operand layout of mfma_f32_16x16x16bf16_1k (k=quad*4+j). O partial per
// wave (disjoint keys), reduced cross-wave ONCE per block via reused LDS.
// ---------------------------------------------------------------------------
__global__ __launch_bounds__(256, 3) void attn_mfma7(
    const unsigned short* __restrict__ Qtb, const unsigned short* __restrict__ Kb,
    const unsigned short* __restrict__ Vtb, unsigned short* __restrict__ AOb) {
  // [0..1] = K double-buffer, [2..3] = V double-buffer (32 KB, contiguous;
  // reused as fp32 O-reduction scratch in the epilogue)
  __shared__ __align__(16) unsigned short KVs[4][64 * 64];
  __shared__ float ls[4 * 64];  // per-wave row-sums l[w][qb*16+l15]
  const int tid = threadIdx.x;
  const int w = tid >> 6, lane = tid & 63;
  const int quad = lane >> 4, l15 = lane & 15;

  // balanced (bh, qt) mapping (r7)
  const int bid = blockIdx.x;
  const int xcd = bid & 7;
  const int j = bid >> 3;
  const int c = j & 31, g = j >> 5;
  const int k = c >> 2;
  const int bh = xcd + 8 * (c & 3);
  const int qt = (g == 0) ? (31 - k) : (g == 1) ? (16 + k)
               : (g == 2) ? (15 - k) : k;

  const unsigned short* kbase = Kb + (size_t)bh * SEQ_T * HDIM;
  const unsigned short* vbase = Vtb + (size_t)bh * HDIM * SEQ_T;
  const int sr = tid >> 3;
  const int lc = tid & 7;
  const int scol = lc * 8;
  const int swc = (lc ^ (sr & 7)) * 8;

  // Q B-fragments for all 4 q-blocks, both d-halves (registers, once)
  bf16x8 qf[4][2];
#pragma unroll
  for (int qb = 0; qb < 4; ++qb) {
#pragma unroll
    for (int h = 0; h < 2; ++h) {
      unsigned short qraw[8];
      const unsigned short* qp = Qtb +
          ((size_t)bh * HDIM + h * 32 + quad * 8) * SEQ_T + qt * 64 + qb * 16 +
          l15;
#pragma unroll
      for (int jj = 0; jj < 8; ++jj) qraw[jj] = qp[(size_t)jj * SEQ_T];
      qf[qb][h] = *(const bf16x8*)qraw;
    }
  }

  f32x4 O[4][4];  // [dvb][qb], partial over this wave's keys
#pragma unroll
  for (int dvb = 0; dvb < 4; ++dvb)
#pragma unroll
    for (int qb = 0; qb < 4; ++qb) O[dvb][qb] = (f32x4){0.f, 0.f, 0.f, 0.f};
  float l4[4] = {0.f, 0.f, 0.f, 0.f};

  const int myrowK = w * 16 + l15;          // this wave's K fragment row
  const int kc0 = (quad ^ (myrowK & 7)) * 8;
  const int kc1 = ((quad + 4) ^ (myrowK & 7)) * 8;
  const int vchunk = 2 * w + (quad >> 1);   // logical 16B chunk of V row
  const int vsub = (quad & 1) * 4;

  // stage tile 0
  uint4 rk0, rk1, rv0, rv1;
  {
    const unsigned short* kp = kbase + (size_t)sr * 64 + scol;
    rk0 = *(const uint4*)kp;
    rk1 = *(const uint4*)(kp + 32 * 64);
    const unsigned short* vp = vbase + (size_t)sr * SEQ_T + scol;
    rv0 = *(const uint4*)vp;
    rv1 = *(const uint4*)(vp + 32 * SEQ_T);
  }
  *(uint4*)&KVs[0][sr * 64 + swc] = rk0;
  *(uint4*)&KVs[0][(sr + 32) * 64 + swc] = rk1;
  *(uint4*)&KVs[2][sr * 64 + swc] = rv0;
  *(uint4*)&KVs[2][(sr + 32) * 64 + swc] = rv1;
  __syncthreads();

  for (int i = 0; i <= qt; ++i) {
    const int cur = i & 1;
    const bool diag = (i == qt);

    if (i < qt) {  // prefetch next tile into registers
      const int nkt = i + 1;
      const unsigned short* kp = kbase + (size_t)(nkt * 64 + sr) * 64 + scol;
      rk0 = *(const uint4*)kp;
      rk1 = *(const uint4*)(kp + 32 * 64);
      const unsigned short* vp = vbase + (size_t)sr * SEQ_T + nkt * 64 + scol;
      rv0 = *(const uint4*)vp;
      rv1 = *(const uint4*)(vp + 32 * SEQ_T);
    }

    // K A-frags (this wave's 16 keys), V A-frags (4 dv-blocks x 4 keys)
    bf16x8 kf0 = *(const bf16x8*)&KVs[cur][myrowK * 64 + kc0];
    bf16x8 kf1 = *(const bf16x8*)&KVs[cur][myrowK * 64 + kc1];
    bf16x4 vf[4];
#pragma unroll
    for (int dvb = 0; dvb < 4; ++dvb) {
      int row = dvb * 16 + l15;
      vf[dvb] = *(const bf16x4*)&KVs[2 + cur][row * 64 +
                                             ((vchunk ^ (row & 7)) * 8) + vsub];
    }

#pragma unroll
    for (int qb = 0; qb < 4; ++qb) {
      f32x4 S = {0.f, 0.f, 0.f, 0.f};
      S = __builtin_amdgcn_mfma_f32_16x16x32_bf16(kf0, qf[qb][0], S, 0, 0, 0);
      S = __builtin_amdgcn_mfma_f32_16x16x32_bf16(kf1, qf[qb][1], S, 0, 0, 0);
      float pp[4];
#pragma unroll
      for (int r = 0; r < 4; ++r) {
        float p = __builtin_amdgcn_exp2f(S[r] - SSHIFT);
        if (diag) {
          int key_rel = w * 16 + quad * 4 + r;
          int q_rel = qb * 16 + l15;
          if (key_rel > q_rel) p = 0.f;
        }
        pp[r] = p;
      }
      l4[qb] += pp[0] + pp[1] + pp[2] + pp[3];
      uint2 pk = {pack_bf16(pp[0], pp[1]), pack_bf16(pp[2], pp[3])};
      bf16x4 pf = *(const bf16x4*)&pk;
#pragma unroll
      for (int dvb = 0; dvb < 4; ++dvb)
        O[dvb][qb] = __builtin_amdgcn_mfma_f32_16x16x16bf16_1k(
            vf[dvb], pf, O[dvb][qb], 0, 0, 0);
    }

    if (i < qt) {  // commit prefetched tile into alternate buffers
      const int nxt = cur ^ 1;
      *(uint4*)&KVs[nxt][sr * 64 + swc] = rk0;
      *(uint4*)&KVs[nxt][(sr + 32) * 64 + swc] = rk1;
      *(uint4*)&KVs[2 + nxt][sr * 64 + swc] = rv0;
      *(uint4*)&KVs[2 + nxt][(sr + 32) * 64 + swc] = rv1;
    }
    __syncthreads();  // also guards epilogue reuse of KVs after last tile
  }

  // ---- cross-wave reduction (once per block) ----
  // l: reduce over quads in-register, publish per wave
#pragma unroll
  for (int qb = 0; qb < 4; ++qb) {
    float v = l4[qb];
    v += __shfl_xor(v, 16);
    v += __shfl_xor(v, 32);
    l4[qb] = v;
  }
  if (quad == 0) {
#pragma unroll
    for (int qb = 0; qb < 4; ++qb) ls[w * 64 + qb * 16 + l15] = l4[qb];
  }
  // O: waves 0,1 write slots; waves 2,3 add; then each wave finalizes dvb=w
  float* Ored = (float*)&KVs[0][0];  // 2 slots x 4 dvb x 4 qb x 64 lanes x 4
  auto oslot = [&](int slot, int dvb, int qb) {
    return Ored + ((((slot * 4 + dvb) * 4 + qb) * 64) + lane) * 4;
  };
  if (w < 2) {
#pragma unroll
    for (int dvb = 0; dvb < 4; ++dvb)
#pragma unroll
      for (int qb = 0; qb < 4; ++qb) *(f32x4*)oslot(w, dvb, qb) = O[dvb][qb];
  }
  __syncthreads();
  if (w >= 2) {
    const int slot = w - 2;
#pragma unroll
    for (int dvb = 0; dvb < 4; ++dvb)
#pragma unroll
      for (int qb = 0; qb < 4; ++qb) {
        f32x4 t = *(const f32x4*)oslot(slot, dvb, qb);
        t += O[dvb][qb];
        *(f32x4*)oslot(slot, dvb, qb) = t;
      }
  }
  __syncthreads();

  const int bb = bh >> 3, h8 = bh & 7;
#pragma unroll
  for (int qb = 0; qb < 4; ++qb) {
    f32x4 a = *(const f32x4*)oslot(0, w, qb);
    f32x4 b = *(const f32x4*)oslot(1, w, qb);
    float lt = ls[0 * 64 + qb * 16 + l15] + ls[1 * 64 + qb * 16 + l15] +
               ls[2 * 64 + qb * 16 + l15] + ls[3 * 64 + qb * 16 + l15];
    float inv = 1.0f / lt;
    int qrow = qt * 64 + qb * 16 + l15;
    ushort4 o4 = {f2bf((a[0] + b[0]) * inv), f2bf((a[1] + b[1]) * inv),
                  f2bf((a[2] + b[2]) * inv), f2bf((a[3] + b[3]) * inv)};
    *(ushort4*)(AOb + ((size_t)bb * SEQ_T + qrow) * D_MODEL + (h8 << 6) +
                w * 16 + quad * 4) = o4;
  }
}

// ---------------------------------------------------------------------------
// Kernel 3 (r7): output projection, bf16 MFMA. 64x128 tile, BK=64 swizzled.
// ---------------------------------------------------------------------------
__global__ __launch_bounds__(256) void gemm_out_mfma(
    const unsigned short* __restrict__ AOb, const unsigned short* __restrict__ Wot,
    const float* __restrict__ bias, float* __restrict__ out) {
  __shared__ unsigned short As[64 * 64];
  __shared__ unsigned short Bs[128 * 64];
  const int tid = threadIdx.x;
  const int w = tid >> 6, lane = tid & 63;
  const int quad = lane >> 4, l15 = lane & 15;
  const int m0 = blockIdx.x * 64, n0 = blockIdx.y * 128;

  const int srow = tid >> 3;
  const int schunk = (tid & 7) ^ (srow & 7);
  const unsigned short* ga = AOb + (size_t)(m0 + srow) * 512 + schunk * 8;
  const unsigned short* gb = Wot + (size_t)(n0 + srow) * 512 + schunk * 8;
  unsigned short* lA = As + tid * 8;
  unsigned short* lB = Bs + tid * 8;

  f32x4 acc[4][2] = {};
  for (int k0 = 0; k0 < 512; k0 += 64) {
#pragma unroll
    for (int rr = 0; rr < 2; ++rr)
      async_lds16(ga + (size_t)rr * 32 * 512 + k0, lA + rr * 2048);
#pragma unroll
    for (int rr = 0; rr < 4; ++rr)
      async_lds16(gb + (size_t)rr * 32 * 512 + k0, lB + rr * 2048);
    __syncthreads();
    bf16x8 af[4][2], bfr[2][2];
#pragma unroll
    for (int mb = 0; mb < 4; ++mb) {
      int row = mb * 16 + l15;
#pragma unroll
      for (int kk = 0; kk < 2; ++kk) {
        int slot = (kk * 4 + quad) ^ (row & 7);
        af[mb][kk] = *(const bf16x8*)&As[row * 64 + slot * 8];
      }
    }
#pragma unroll
    for (int nb = 0; nb < 2; ++nb) {
      int row = w * 32 + nb * 16 + l15;
#pragma unroll
      for (int kk = 0; kk < 2; ++kk) {
        int slot = (kk * 4 + quad) ^ (row & 7);
        bfr[nb][kk] = *(const bf16x8*)&Bs[row * 64 + slot * 8];
      }
    }
#pragma unroll
    for (int mb = 0; mb < 4; ++mb)
#pragma unroll
      for (int nb = 0; nb < 2; ++nb) {
        acc[mb][nb] = __builtin_amdgcn_mfma_f32_16x16x32_bf16(
            af[mb][0], bfr[nb][0], acc[mb][nb], 0, 0, 0);
        acc[mb][nb] = __builtin_amdgcn_mfma_f32_16x16x32_bf16(
            af[mb][1], bfr[nb][1], acc[mb][nb], 0, 0, 0);
      }
    __syncthreads();
  }

  const int cbase = n0 + w * 32;
  float bv[2];
#pragma unroll
  for (int nb = 0; nb < 2; ++nb) bv[nb] = bias[cbase + nb * 16 + l15];
#pragma unroll
  for (int mb = 0; mb < 4; ++mb)
#pragma unroll
    for (int nb = 0; nb < 2; ++nb)
#pragma unroll
      for (int r = 0; r < 4; ++r)
        out[(size_t)(m0 + mb * 16 + quad * 4 + r) * 512 + cbase + nb * 16 +
            l15] = acc[mb][nb][r] + bv[nb];
}

// ---------------------------------------------------------------------------
extern "C" void kernel_launch(void* const* d_in, const int* in_sizes, int n_in,
                              void* d_out, int out_size, void* d_ws,
                              size_t ws_size, hipStream_t stream) {
  const float* x     = (const float*)d_in[0];
  const float* W_qkv = (const float*)d_in[1];
  const float* b_qkv = (const float*)d_in[2];
  const float* W_out = (const float*)d_in[3];
  const float* b_out = (const float*)d_in[4];
  float* out = (float*)d_out;

  const size_t NX = (size_t)4 * SEQ_T * D_MODEL;        // 4,194,304
  unsigned short* xb   = (unsigned short*)d_ws;          // [8192][512]
  unsigned short* Wqkt = xb + NX;                        // [1536][512]
  unsigned short* Wot  = Wqkt + (size_t)1536 * 512;      // [512][512]
  unsigned short* Qtb  = Wot + (size_t)512 * 512;        // [bh][d][t]
  unsigned short* Kb   = Qtb + NX;                       // [bh][t][d]
  unsigned short* Vtb  = Kb + NX;                        // [bh][dv][t]
  unsigned short* AOb  = Vtb + NX;                       // [8192][512]

  prep_kernel<<<2304, 256, 0, stream>>>(x, W_qkv, W_out, xb, Wqkt, Wot);
  gemm_qkv_mfma<<<dim3(64, 12), 256, 0, stream>>>(xb, Wqkt, b_qkv, Qtb, Kb,
                                                  Vtb);
  attn_mfma7<<<dim3(1024), 256, 0, stream>>>(Qtb, Kb, Vtb, AOb);
  gemm_out_mfma<<<dim3(128, 4), 256, 0, stream>>>(AOb, Wot, b_out, out);
}